// Round 6
// baseline (157.393 us; speedup 1.0000x reference)
//
#include <hip/hip_runtime.h>

// Affine-IFS scan, single-pass (K=1): one wave = 64 points, full T=512 steps.
// R4->R5: dropped the compose/replay decomposition (2x FLOPs, 2x LDS passes,
// 32KB staging, 3 barriers) in favor of 1x-work serial replay with:
//   - 512B LDS transform table (float4 pairs, b128 reads, broadcast-heavy)
//   - depth-2 rolling register prefetch of code (16 steps in flight, covers
//     ~900cyc HBM latency with ~800cyc of compute+LDS per 2-group body)
// Grid = 256 blocks x 64 threads = 1 wave/CU; memory-bound target ~21us.

#define B_PTS 16384
#define T_STEPS 512
#define N_TR 16
#define GRP 8

__global__ __launch_bounds__(64, 1)
void ifs_single_pass(const float* __restrict__ init_pts,
                     const float* __restrict__ weights,
                     const float* __restrict__ biases,
                     const float* __restrict__ opac,
                     const int*   __restrict__ code,
                     float*       __restrict__ out)
{
    __shared__ float4 tabA[N_TR];   // w00,w01,w10,w11
    __shared__ float4 tabB[N_TR];   // bx,by,op,0

    const int lane = threadIdx.x;
    const int b    = blockIdx.x * 64 + lane;

    if (lane < N_TR) {
        tabA[lane] = make_float4(weights[lane*4+0], weights[lane*4+1],
                                 weights[lane*4+2], weights[lane*4+3]);
        tabB[lane] = make_float4(biases[lane*2+0], biases[lane*2+1],
                                 opac[lane], 0.f);
    }
    __syncthreads();   // single wave: compiles to waitcnt only

    const float2 p0 = *reinterpret_cast<const float2*>(&init_pts[(size_t)b * 2]);
    float px = p0.x, py = p0.y;

    // depth-2 rolling prefetch: c0 = steps [t0, t0+8), c1 = [t0+8, t0+16)
    int c0[GRP], c1[GRP];
    #pragma unroll
    for (int g = 0; g < GRP; ++g) c0[g] = code[(size_t)g * B_PTS + b];
    #pragma unroll
    for (int g = 0; g < GRP; ++g) c1[g] = code[(size_t)(GRP + g) * B_PTS + b];

    float* op = out + (size_t)b * 3;
    const size_t step_stride = (size_t)B_PTS * 3;

    for (int t0 = 0; t0 < T_STEPS; t0 += 2 * GRP) {
        // issue next 16 code loads first (clamped: tail re-reads row 511, harmless)
        int n0[GRP], n1[GRP];
        #pragma unroll
        for (int g = 0; g < GRP; ++g) {
            const int tl = t0 + 2 * GRP + g;
            n0[g] = code[(size_t)(tl < T_STEPS ? tl : T_STEPS - 1) * B_PTS + b];
        }
        #pragma unroll
        for (int g = 0; g < GRP; ++g) {
            const int tl = t0 + 3 * GRP + g;
            n1[g] = code[(size_t)(tl < T_STEPS ? tl : T_STEPS - 1) * B_PTS + b];
        }

        // compute group 0 (uses c0, already resident)
        #pragma unroll
        for (int g = 0; g < GRP; ++g) {
            const int idx   = c0[g];
            const float4 A  = tabA[idx];
            const float4 Bv = tabB[idx];
            const float nx = fmaf(A.x, px, fmaf(A.y, py, Bv.x));
            const float ny = fmaf(A.z, px, fmaf(A.w, py, Bv.y));
            px = nx; py = ny;
            op[0] = fmaf(px, 0.5f, 0.5f);
            op[1] = fmaf(py, 0.5f, 0.5f);
            op[2] = Bv.z;
            op += step_stride;
        }
        // compute group 1 (uses c1)
        #pragma unroll
        for (int g = 0; g < GRP; ++g) {
            const int idx   = c1[g];
            const float4 A  = tabA[idx];
            const float4 Bv = tabB[idx];
            const float nx = fmaf(A.x, px, fmaf(A.y, py, Bv.x));
            const float ny = fmaf(A.z, px, fmaf(A.w, py, Bv.y));
            px = nx; py = ny;
            op[0] = fmaf(px, 0.5f, 0.5f);
            op[1] = fmaf(py, 0.5f, 0.5f);
            op[2] = Bv.z;
            op += step_stride;
        }

        #pragma unroll
        for (int g = 0; g < GRP; ++g) { c0[g] = n0[g]; c1[g] = n1[g]; }
    }
}

extern "C" void kernel_launch(void* const* d_in, const int* in_sizes, int n_in,
                              void* d_out, int out_size, void* d_ws, size_t ws_size,
                              hipStream_t stream) {
    const float* init_pts = (const float*)d_in[0];
    const float* weights  = (const float*)d_in[1];
    const float* biases   = (const float*)d_in[2];
    const float* opac     = (const float*)d_in[3];
    const int*   code     = (const int*)d_in[4];
    float*       out      = (float*)d_out;

    ifs_single_pass<<<B_PTS / 64, 64, 0, stream>>>(
        init_pts, weights, biases, opac, code, out);
}

// Round 7
// 139.104 us; speedup vs baseline: 1.1315x; 1.1315x over previous
//
#include <hip/hip_runtime.h>

// Affine-IFS scan, decomposed v2. Block = 64 points x 16 waves(=32-step chunks).
// R6->R7 (vs R4 decomposed): (1) code held in 32 VGPRs/lane instead of 32KB LDS
// staging (each wave only needs its own chunk's codes for BOTH compose+replay);
// (2) compose uses a 256-entry pair-composite table (2 steps/iter, half the
// compose VALU+LDS); (3) barriers 3->2. Work tax now ~1.5x instead of 2x.

#define B_PTS 16384
#define T_STEPS 512
#define N_TR 16
#define PTS_PER_BLK 64
#define WAVES 16
#define L_CHUNK 32   // T_STEPS / WAVES
#define THREADS 1024
#define NPAIR 256

__global__ __launch_bounds__(THREADS, 1)
void ifs_scan_v2(const float* __restrict__ init_pts,
                 const float* __restrict__ weights,
                 const float* __restrict__ biases,
                 const float* __restrict__ opac,
                 const int*   __restrict__ code,
                 float*       __restrict__ out)
{
    __shared__ float4 tabA[N_TR];                 // w00,w01,w10,w11
    __shared__ float4 tabB[N_TR];                 // bx,by,op,0
    __shared__ float4 pairA[NPAIR];               // A_j*A_i
    __shared__ float2 pairB[NPAIR];               // A_j*b_i + b_j
    __shared__ float4 mapsA[WAVES][PTS_PER_BLK];  // chunk map M
    __shared__ float2 mapsB[WAVES][PTS_PER_BLK];  // chunk map v
    // LDS total ~31.2 KB

    const int tid  = threadIdx.x;
    const int lane = tid & 63;
    const int wv   = tid >> 6;
    const int base = blockIdx.x * PTS_PER_BLK;
    const int b    = base + lane;
    const int t0   = wv * L_CHUNK;

    // ---- per-lane code for this wave's chunk (coalesced 256B rows, stay in VGPRs) ----
    int c[L_CHUNK];
    #pragma unroll
    for (int s = 0; s < L_CHUNK; ++s)
        c[s] = code[(size_t)(t0 + s) * B_PTS + b];

    // ---- build tables from global (L2-resident, once) ----
    if (tid < N_TR) {
        tabA[tid] = make_float4(weights[tid*4+0], weights[tid*4+1],
                                weights[tid*4+2], weights[tid*4+3]);
        tabB[tid] = make_float4(biases[tid*2+0], biases[tid*2+1], opac[tid], 0.f);
    }
    if (tid >= 64 && tid < 64 + NPAIR) {          // waves 1..4 build pair table
        const int n = tid - 64;
        const int i = n & 15, j = n >> 4;         // apply i then j
        const float ai = weights[i*4+0], bi = weights[i*4+1];
        const float ci = weights[i*4+2], di = weights[i*4+3];
        const float aj = weights[j*4+0], bj = weights[j*4+1];
        const float cj = weights[j*4+2], dj = weights[j*4+3];
        const float bxi = biases[i*2+0], byi = biases[i*2+1];
        const float bxj = biases[j*2+0], byj = biases[j*2+1];
        pairA[n] = make_float4(aj*ai + bj*ci, aj*bi + bj*di,
                               cj*ai + dj*ci, cj*bi + dj*di);
        pairB[n] = make_float2(aj*bxi + bj*byi + bxj,
                               cj*bxi + dj*byi + byj);
    }
    __syncthreads();

    // ---- compose chunk map via pair table: 16 iters cover 32 steps ----
    float m00 = 1.f, m01 = 0.f, m10 = 0.f, m11 = 1.f, vx = 0.f, vy = 0.f;
    #pragma unroll
    for (int k = 0; k < L_CHUNK / 2; ++k) {
        const int pidx = (c[2*k+1] << 4) | c[2*k];
        const float4 P = pairA[pidx];
        const float2 V = pairB[pidx];
        const float n00 = P.x * m00 + P.y * m10;
        const float n01 = P.x * m01 + P.y * m11;
        const float n10 = P.z * m00 + P.w * m10;
        const float n11 = P.z * m01 + P.w * m11;
        const float nvx = P.x * vx + P.y * vy + V.x;
        const float nvy = P.z * vx + P.w * vy + V.y;
        m00 = n00; m01 = n01; m10 = n10; m11 = n11; vx = nvx; vy = nvy;
    }
    mapsA[wv][lane] = make_float4(m00, m01, m10, m11);
    mapsB[wv][lane] = make_float2(vx, vy);
    __syncthreads();

    // ---- prefix: apply chunk maps [0..wv) to init point ----
    const float2 p0 = *reinterpret_cast<const float2*>(&init_pts[(size_t)b * 2]);
    float px = p0.x, py = p0.y;
    for (int q = 0; q < wv; ++q) {      // wave-uniform trip count
        const float4 M = mapsA[q][lane];
        const float2 V = mapsB[q][lane];
        const float nx = M.x * px + M.y * py + V.x;
        const float ny = M.z * px + M.w * py + V.y;
        px = nx; py = ny;
    }

    // ---- replay chunk from register codes, write output ----
    float* op = out + (size_t)((size_t)t0 * B_PTS + b) * 3;
    #pragma unroll 8
    for (int s = 0; s < L_CHUNK; ++s) {
        const int idx   = c[s];
        const float4 A  = tabA[idx];
        const float4 Bv = tabB[idx];
        const float nx = fmaf(A.x, px, fmaf(A.y, py, Bv.x));
        const float ny = fmaf(A.z, px, fmaf(A.w, py, Bv.y));
        px = nx; py = ny;
        op[0] = fmaf(px, 0.5f, 0.5f);
        op[1] = fmaf(py, 0.5f, 0.5f);
        op[2] = Bv.z;
        op += (size_t)B_PTS * 3;
    }
}

extern "C" void kernel_launch(void* const* d_in, const int* in_sizes, int n_in,
                              void* d_out, int out_size, void* d_ws, size_t ws_size,
                              hipStream_t stream) {
    const float* init_pts = (const float*)d_in[0];
    const float* weights  = (const float*)d_in[1];
    const float* biases   = (const float*)d_in[2];
    const float* opac     = (const float*)d_in[3];
    const int*   code     = (const int*)d_in[4];
    float*       out      = (float*)d_out;

    ifs_scan_v2<<<B_PTS / PTS_PER_BLK, THREADS, 0, stream>>>(
        init_pts, weights, biases, opac, code, out);
}